// Round 1
// baseline (91.791 us; speedup 1.0000x reference)
//
#include <hip/hip_runtime.h>
#include <hip/hip_bf16.h>

#define NBINS 10
#define C 128

// d_ws layout: [0..9] counts (u64), [10..19] sum_conf in 32.32 fixed point (u64),
//              [20..29] sum_acc (u64)

__global__ __launch_bounds__(256) void ece_main_kernel(
    const float* __restrict__ logits, const int* __restrict__ targets,
    unsigned long long* __restrict__ gbins, int N) {
  __shared__ unsigned long long sbins[3 * NBINS];
  const int tid = threadIdx.x;
  for (int i = tid; i < 3 * NBINS; i += blockDim.x) sbins[i] = 0ull;
  __syncthreads();

  const int lane = tid & 63;
  const int wavesPerBlock = blockDim.x >> 6;
  const int wid = blockIdx.x * wavesPerBlock + (tid >> 6);
  const int nwaves = gridDim.x * wavesPerBlock;

  for (int row = wid; row < N; row += nwaves) {
    const float2 v = *reinterpret_cast<const float2*>(
        logits + (size_t)row * C + lane * 2);

    // local max + argmax (first-occurrence tie-break, matching jnp.argmax)
    float m;
    int idx;
    if (v.y > v.x) { m = v.y; idx = lane * 2 + 1; }
    else           { m = v.x; idx = lane * 2; }

    // wave reduce max + argmax
    #pragma unroll
    for (int off = 1; off < 64; off <<= 1) {
      float om = __shfl_xor(m, off);
      int   oi = __shfl_xor(idx, off);
      if (om > m || (om == m && oi < idx)) { m = om; idx = oi; }
    }

    // sum of exp(x - max)
    float s = __expf(v.x - m) + __expf(v.y - m);
    #pragma unroll
    for (int off = 1; off < 64; off <<= 1) s += __shfl_xor(s, off);

    if (lane == 0) {
      float conf = 1.0f / s;                       // = max(softmax(row))
      int bin = (int)ceilf(conf * 10.0f) - 1;      // (k/10,(k+1)/10] -> k
      bin = min(max(bin, 0), NBINS - 1);
      unsigned long long acc = (targets[row] == idx) ? 1ull : 0ull;
      unsigned long long confq =
          (unsigned long long)((double)conf * 4294967296.0);
      atomicAdd(&sbins[bin], 1ull);
      atomicAdd(&sbins[NBINS + bin], confq);
      atomicAdd(&sbins[2 * NBINS + bin], acc);
    }
  }
  __syncthreads();
  for (int i = tid; i < 3 * NBINS; i += blockDim.x) {
    unsigned long long v = sbins[i];
    if (v) atomicAdd(&gbins[i], v);
  }
}

__global__ void ece_final_kernel(const unsigned long long* __restrict__ gbins,
                                 float* __restrict__ out, int N) {
  const int t = threadIdx.x;
  float per = 0.0f;
  if (t < NBINS) {
    double cnt = (double)gbins[t];
    double sc = (double)gbins[NBINS + t] * (1.0 / 4294967296.0);
    double sa = (double)gbins[2 * NBINS + t];
    double safe = cnt > 0.0 ? cnt : 1.0;
    double avg_c = sc / safe;
    double avg_a = sa / safe;
    double prop = cnt / (double)N;
    per = (cnt > 0.0) ? (float)(fabs(avg_c - avg_a) * prop) : 0.0f;
  }
  #pragma unroll
  for (int off = 1; off < 16; off <<= 1) per += __shfl_xor(per, off);
  if (t == 0) out[0] = per;
}

extern "C" void kernel_launch(void* const* d_in, const int* in_sizes, int n_in,
                              void* d_out, int out_size, void* d_ws, size_t ws_size,
                              hipStream_t stream) {
  const float* logits = (const float*)d_in[0];
  const int* targets = (const int*)d_in[1];
  float* out = (float*)d_out;
  unsigned long long* gbins = (unsigned long long*)d_ws;

  const int N = in_sizes[1];  // 262144 rows (targets element count)

  hipMemsetAsync(gbins, 0, 3 * NBINS * sizeof(unsigned long long), stream);

  // 4 waves/block, grid-stride over rows; ~2048 blocks saturates 256 CUs.
  const int block = 256;
  const int wavesPerBlock = block / 64;
  int grid = (N + wavesPerBlock - 1) / wavesPerBlock;
  if (grid > 2048) grid = 2048;

  ece_main_kernel<<<grid, block, 0, stream>>>(logits, targets, gbins, N);
  ece_final_kernel<<<1, 64, 0, stream>>>(gbins, out, N);
}

// Round 2
// 60.538 us; speedup vs baseline: 1.5162x; 1.5162x over previous
//
#include <hip/hip_runtime.h>
#include <hip/hip_bf16.h>

#define NBINS 10
#define C 128

// d_ws layout: [0..9] counts (u64), [10..19] sum_conf in 32.32 fixed point (u64),
//              [20..29] sum_acc (u64)

__global__ __launch_bounds__(256) void ece_main_kernel(
    const float* __restrict__ logits, const int* __restrict__ targets,
    unsigned long long* __restrict__ gbins, int N) {
  __shared__ unsigned long long sbins[3 * NBINS];
  const int tid = threadIdx.x;
  for (int i = tid; i < 3 * NBINS; i += blockDim.x) sbins[i] = 0ull;
  __syncthreads();

  const int lane = tid & 63;
  const int half = lane >> 5;   // which row of the pair this lane works on
  const int hl = lane & 31;     // lane index within the 32-lane half
  const int wavesPerBlock = blockDim.x >> 6;
  const int wid = blockIdx.x * wavesPerBlock + (tid >> 6);
  const int nwaves = gridDim.x * wavesPerBlock;

  const int npairs = N >> 1;

  for (int p = wid; p < npairs; p += nwaves) {
    const int row = p * 2 + half;
    // wave reads 1024 contiguous bytes: lanes 0..31 -> row 2p, 32..63 -> row 2p+1
    const float4 v = *reinterpret_cast<const float4*>(
        logits + (size_t)p * (2 * C) + half * C + hl * 4);

    // in-lane max + first-occurrence argmax over 4 elements
    float m = v.x; int c = 0;
    if (v.y > m) { m = v.y; c = 1; }
    if (v.z > m) { m = v.z; c = 2; }
    if (v.w > m) { m = v.w; c = 3; }
    const float lm = m;
    const int col = (hl << 2) + c;

    // half-wave value max (xor masks <=16 keep lanes within their 32-lane half)
    #pragma unroll
    for (int off = 1; off <= 16; off <<= 1) m = fmaxf(m, __shfl_xor(m, off));

    // first-occurrence argmax: lowest flagged lane in this half
    const unsigned long long b = __ballot(lm == m);
    const unsigned slice = (unsigned)(b >> (half << 5));
    const int srcl = (half << 5) + (__ffs(slice) - 1);
    const int wcol = __shfl(col, srcl);

    // sum of exp(x - max) over the row (half-wave)
    float s = (__expf(v.x - m) + __expf(v.y - m)) +
              (__expf(v.z - m) + __expf(v.w - m));
    #pragma unroll
    for (int off = 1; off <= 16; off <<= 1) s += __shfl_xor(s, off);

    if (hl == 0) {
      const float conf = 1.0f / s;               // = max(softmax(row))
      int bin = (int)ceilf(conf * 10.0f) - 1;    // (k/10,(k+1)/10] -> k
      bin = min(max(bin, 0), NBINS - 1);
      const unsigned long long acc = (targets[row] == wcol) ? 1ull : 0ull;
      const unsigned long long confq =
          (unsigned long long)((double)conf * 4294967296.0);
      atomicAdd(&sbins[bin], 1ull);
      atomicAdd(&sbins[NBINS + bin], confq);
      atomicAdd(&sbins[2 * NBINS + bin], acc);
    }
  }

  // odd-N leftover row (not hit for N=262144; kept for generality)
  if ((N & 1) && wid == 0 && half == 0) {
    const int row = N - 1;
    const float4 v = *reinterpret_cast<const float4*>(
        logits + (size_t)row * C + hl * 4);
    float m = v.x; int c = 0;
    if (v.y > m) { m = v.y; c = 1; }
    if (v.z > m) { m = v.z; c = 2; }
    if (v.w > m) { m = v.w; c = 3; }
    const float lm = m;
    const int col = (hl << 2) + c;
    #pragma unroll
    for (int off = 1; off <= 16; off <<= 1) m = fmaxf(m, __shfl_xor(m, off));
    const unsigned long long b = __ballot(lm == m);
    const unsigned slice = (unsigned)b;
    const int srcl = __ffs(slice) - 1;
    const int wcol = __shfl(col, srcl);
    float s = (__expf(v.x - m) + __expf(v.y - m)) +
              (__expf(v.z - m) + __expf(v.w - m));
    #pragma unroll
    for (int off = 1; off <= 16; off <<= 1) s += __shfl_xor(s, off);
    if (hl == 0) {
      const float conf = 1.0f / s;
      int bin = (int)ceilf(conf * 10.0f) - 1;
      bin = min(max(bin, 0), NBINS - 1);
      const unsigned long long acc = (targets[row] == wcol) ? 1ull : 0ull;
      const unsigned long long confq =
          (unsigned long long)((double)conf * 4294967296.0);
      atomicAdd(&sbins[bin], 1ull);
      atomicAdd(&sbins[NBINS + bin], confq);
      atomicAdd(&sbins[2 * NBINS + bin], acc);
    }
  }

  __syncthreads();
  for (int i = tid; i < 3 * NBINS; i += blockDim.x) {
    unsigned long long v = sbins[i];
    if (v) atomicAdd(&gbins[i], v);
  }
}

__global__ void ece_final_kernel(const unsigned long long* __restrict__ gbins,
                                 float* __restrict__ out, int N) {
  const int t = threadIdx.x;
  float per = 0.0f;
  if (t < NBINS) {
    double cnt = (double)gbins[t];
    double sc = (double)gbins[NBINS + t] * (1.0 / 4294967296.0);
    double sa = (double)gbins[2 * NBINS + t];
    double safe = cnt > 0.0 ? cnt : 1.0;
    double avg_c = sc / safe;
    double avg_a = sa / safe;
    double prop = cnt / (double)N;
    per = (cnt > 0.0) ? (float)(fabs(avg_c - avg_a) * prop) : 0.0f;
  }
  #pragma unroll
  for (int off = 1; off < 16; off <<= 1) per += __shfl_xor(per, off);
  if (t == 0) out[0] = per;
}

extern "C" void kernel_launch(void* const* d_in, const int* in_sizes, int n_in,
                              void* d_out, int out_size, void* d_ws, size_t ws_size,
                              hipStream_t stream) {
  const float* logits = (const float*)d_in[0];
  const int* targets = (const int*)d_in[1];
  float* out = (float*)d_out;
  unsigned long long* gbins = (unsigned long long*)d_ws;

  const int N = in_sizes[1];  // 262144 rows

  hipMemsetAsync(gbins, 0, 3 * NBINS * sizeof(unsigned long long), stream);

  const int block = 256;  // 4 waves/block
  int grid = 2048;        // 8192 waves = 32/CU * 256 CU, exactly fills the machine
  const int npairs = N >> 1;
  const int wavesNeeded = (npairs + 0);
  int maxGrid = (wavesNeeded + 3) / 4;
  if (grid > maxGrid) grid = maxGrid > 0 ? maxGrid : 1;

  ece_main_kernel<<<grid, block, 0, stream>>>(logits, targets, gbins, N);
  ece_final_kernel<<<1, 64, 0, stream>>>(gbins, out, N);
}

// Round 3
// 55.770 us; speedup vs baseline: 1.6459x; 1.0855x over previous
//
#include <hip/hip_runtime.h>
#include <hip/hip_bf16.h>

#define NBINS 10
#define C 128
#define U 4  // pairs per wave-iteration (ILP)

// d_ws layout: [0..9] counts (u64), [10..19] sum_conf in 32.32 fixed point (u64),
//              [20..29] sum_acc (u64)

__global__ __launch_bounds__(256) void ece_main_kernel(
    const float* __restrict__ logits, const int* __restrict__ targets,
    unsigned long long* __restrict__ gbins, int N) {
  __shared__ unsigned long long sbins[3 * NBINS];
  const int tid = threadIdx.x;
  for (int i = tid; i < 3 * NBINS; i += blockDim.x) sbins[i] = 0ull;
  __syncthreads();

  const int lane = tid & 63;
  const int half = lane >> 5;   // which row of each pair this lane works on
  const int hl = lane & 31;     // lane index within the 32-lane half
  const int wavesPerBlock = blockDim.x >> 6;
  const int wid = blockIdx.x * wavesPerBlock + (tid >> 6);
  const int nwaves = gridDim.x * wavesPerBlock;

  const int npairs = N >> 1;

  for (int p0 = wid * U; p0 < npairs; p0 += nwaves * U) {
    float4 v[U];
    int pp[U];
    bool valid[U];
    #pragma unroll
    for (int u = 0; u < U; ++u) {
      const int p = p0 + u;
      valid[u] = (p < npairs);
      pp[u] = valid[u] ? p : (npairs - 1);
      v[u] = *reinterpret_cast<const float4*>(
          logits + (size_t)pp[u] * (2 * C) + half * C + hl * 4);
    }

    // in-lane max + first-occurrence argmax over 4 elements
    float m[U], lm[U];
    int col[U];
    #pragma unroll
    for (int u = 0; u < U; ++u) {
      float mm = v[u].x; int c = 0;
      if (v[u].y > mm) { mm = v[u].y; c = 1; }
      if (v[u].z > mm) { mm = v[u].z; c = 2; }
      if (v[u].w > mm) { mm = v[u].w; c = 3; }
      m[u] = mm; lm[u] = mm; col[u] = (hl << 2) + c;
    }

    // half-wave value max: 4 independent DPP chains interleaved
    #pragma unroll
    for (int off = 1; off <= 16; off <<= 1) {
      #pragma unroll
      for (int u = 0; u < U; ++u) m[u] = fmaxf(m[u], __shfl_xor(m[u], off));
    }

    // first-occurrence argmax via ballot (lowest flagged lane in this half)
    int wcol[U];
    #pragma unroll
    for (int u = 0; u < U; ++u) {
      const unsigned long long b = __ballot(lm[u] == m[u]);
      const unsigned slice = (unsigned)(b >> (half << 5));
      const int srcl = (half << 5) + (__ffs(slice) - 1);
      wcol[u] = __shfl(col[u], srcl);
    }

    // sum of exp(x - max): independent exps, then 4 interleaved add chains
    float s[U];
    #pragma unroll
    for (int u = 0; u < U; ++u)
      s[u] = (__expf(v[u].x - m[u]) + __expf(v[u].y - m[u])) +
             (__expf(v[u].z - m[u]) + __expf(v[u].w - m[u]));
    #pragma unroll
    for (int off = 1; off <= 16; off <<= 1) {
      #pragma unroll
      for (int u = 0; u < U; ++u) s[u] += __shfl_xor(s[u], off);
    }

    #pragma unroll
    for (int u = 0; u < U; ++u) {
      if (valid[u] && hl == 0) {
        const float conf = 1.0f / s[u];            // = max(softmax(row))
        int bin = (int)ceilf(conf * 10.0f) - 1;    // (k/10,(k+1)/10] -> k
        bin = min(max(bin, 0), NBINS - 1);
        const int row = pp[u] * 2 + half;
        const unsigned long long acc = (targets[row] == wcol[u]) ? 1ull : 0ull;
        const unsigned long long confq =
            (unsigned long long)((double)conf * 4294967296.0);
        atomicAdd(&sbins[bin], 1ull);
        atomicAdd(&sbins[NBINS + bin], confq);
        atomicAdd(&sbins[2 * NBINS + bin], acc);
      }
    }
  }

  // odd-N leftover row (not hit for N=262144; kept for generality)
  if ((N & 1) && wid == 0 && half == 0) {
    const int row = N - 1;
    const float4 v = *reinterpret_cast<const float4*>(
        logits + (size_t)row * C + hl * 4);
    float m = v.x; int c = 0;
    if (v.y > m) { m = v.y; c = 1; }
    if (v.z > m) { m = v.z; c = 2; }
    if (v.w > m) { m = v.w; c = 3; }
    const float lmv = m;
    const int col = (hl << 2) + c;
    #pragma unroll
    for (int off = 1; off <= 16; off <<= 1) m = fmaxf(m, __shfl_xor(m, off));
    const unsigned long long b = __ballot(lmv == m);
    const int srcl = __ffs((unsigned)b) - 1;
    const int wcol = __shfl(col, srcl);
    float s = (__expf(v.x - m) + __expf(v.y - m)) +
              (__expf(v.z - m) + __expf(v.w - m));
    #pragma unroll
    for (int off = 1; off <= 16; off <<= 1) s += __shfl_xor(s, off);
    if (hl == 0) {
      const float conf = 1.0f / s;
      int bin = (int)ceilf(conf * 10.0f) - 1;
      bin = min(max(bin, 0), NBINS - 1);
      const unsigned long long acc = (targets[row] == wcol) ? 1ull : 0ull;
      const unsigned long long confq =
          (unsigned long long)((double)conf * 4294967296.0);
      atomicAdd(&sbins[bin], 1ull);
      atomicAdd(&sbins[NBINS + bin], confq);
      atomicAdd(&sbins[2 * NBINS + bin], acc);
    }
  }

  __syncthreads();
  for (int i = tid; i < 3 * NBINS; i += blockDim.x) {
    unsigned long long vv = sbins[i];
    if (vv) atomicAdd(&gbins[i], vv);
  }
}

__global__ void ece_final_kernel(const unsigned long long* __restrict__ gbins,
                                 float* __restrict__ out, int N) {
  const int t = threadIdx.x;
  float per = 0.0f;
  if (t < NBINS) {
    double cnt = (double)gbins[t];
    double sc = (double)gbins[NBINS + t] * (1.0 / 4294967296.0);
    double sa = (double)gbins[2 * NBINS + t];
    double safe = cnt > 0.0 ? cnt : 1.0;
    double avg_c = sc / safe;
    double avg_a = sa / safe;
    double prop = cnt / (double)N;
    per = (cnt > 0.0) ? (float)(fabs(avg_c - avg_a) * prop) : 0.0f;
  }
  #pragma unroll
  for (int off = 1; off < 16; off <<= 1) per += __shfl_xor(per, off);
  if (t == 0) out[0] = per;
}

extern "C" void kernel_launch(void* const* d_in, const int* in_sizes, int n_in,
                              void* d_out, int out_size, void* d_ws, size_t ws_size,
                              hipStream_t stream) {
  const float* logits = (const float*)d_in[0];
  const int* targets = (const int*)d_in[1];
  float* out = (float*)d_out;
  unsigned long long* gbins = (unsigned long long*)d_ws;

  const int N = in_sizes[1];  // 262144 rows

  hipMemsetAsync(gbins, 0, 3 * NBINS * sizeof(unsigned long long), stream);

  const int block = 256;  // 4 waves/block
  int grid = 2048;        // 8192 waves; 16 pairs per wave at N=262144
  const int npairs = N >> 1;
  int maxGrid = (npairs + 4 * U - 1) / (4 * U);
  if (grid > maxGrid) grid = maxGrid > 0 ? maxGrid : 1;

  ece_main_kernel<<<grid, block, 0, stream>>>(logits, targets, gbins, N);
  ece_final_kernel<<<1, 64, 0, stream>>>(gbins, out, N);
}